// Round 1
// baseline (522.563 us; speedup 1.0000x reference)
//
#include <hip/hip_runtime.h>

// TTFS encoder: out[b][t][n] = 1.0f at the first t where the leaky-integrate
// membrane crosses V_TH=1.0, else 0.0f. Membrane resets on every spike but
// output records only the FIRST spike -> output is one-hot (or zero) per
// (b,n) column across t.
//
// Bit-exactness notes (output is {0,1}: one flipped element = absmax 1.0):
//  - decay = fp32(exp(-0.5)) correctly rounded; (1-decay) exact (Sterbenz).
//  - mem update MUST be mul-then-add round-to-nearest, NOT fma:
//    __fmul_rn/__fadd_rn block -ffp-contract=fast.
//  - drive = (x*s)*(1-decay) precomputed once: same rounding every step as
//    reference's per-step current*(1-decay) (deterministic), so identical.
//
// R3 post-mortem: plain vs NT stores = -0.4us (noise). dur_us(522) > largest
// rocprof dispatch (341us re-poison fill) => timed window includes the fill;
// kernel itself is <=~180us vs ~86us write roofline. Store-policy theory dead.
// R4 theory: the only structural difference from the 6.28 TB/s fill is that
// our stores were interleaved with a serially-dependent 6-op/col recurrence.
// This round: Phase 1 runs the exact recurrence in registers (tstar = first
// spike step), Phase 2 is a pure streaming one-hot sweep (2 independent VALU
// ops per element, stores batchable back-to-back, all full-line, write-once).
// Decision rule: dur_us ~430 => interleave was the gate. dur_us ~522 => kernel
// already at fill rate (hidden out-poison fill likely) => ROOFLINE next round.

#define T_STEPS 64
#define N_COLS  1024

typedef float vfloat4 __attribute__((ext_vector_type(4)));

__global__ __launch_bounds__(256) void ttfs_encode_kernel(
    const float* __restrict__ x,
    const float* __restrict__ sens,
    float* __restrict__ out)
{
    const int b   = blockIdx.x;
    const int tid = threadIdx.x;      // 0..255, each owns 4 consecutive cols
    const int n0  = tid * 4;

    const float decay = 0.60653065971263342f;  // fp32(exp(-0.5)), CR
    const float omd   = 1.0f - decay;          // exact (Sterbenz)

    const vfloat4 xv = *reinterpret_cast<const vfloat4*>(x + (size_t)b * N_COLS + n0);
    const vfloat4 sv = *reinterpret_cast<const vfloat4*>(sens + n0);

    // drive_i = (x*s)*(1-decay): two rn muls, matching reference op order.
    float drive[4];
    #pragma unroll
    for (int i = 0; i < 4; ++i)
        drive[i] = __fmul_rn(__fmul_rn(xv[i], sv[i]), omd);

    // ---- Phase 1: exact recurrence in registers only; record first spike. ----
    // Semantics identical to the previous passing kernel:
    //   m = mem*decay + drive (rn mul, rn add); spike = m >= 1.0f;
    //   first spike time -> tstar; mem = spike ? 0 : m (resets on EVERY spike).
    int   tstar[4] = {T_STEPS, T_STEPS, T_STEPS, T_STEPS};  // T_STEPS = never
    float mem[4]   = {0.f, 0.f, 0.f, 0.f};

    #pragma unroll 8
    for (int t = 0; t < T_STEPS; ++t) {
        #pragma unroll
        for (int i = 0; i < 4; ++i) {
            float m = __fadd_rn(__fmul_rn(mem[i], decay), drive[i]);
            const bool spike = (m >= 1.0f);
            if (spike && tstar[i] == T_STEPS) tstar[i] = t;  // first spike only
            mem[i] = spike ? 0.0f : m;
        }
    }

    // ---- Phase 2: pure streaming one-hot store sweep (fill-like). ----
    // No cross-iteration dependence: ov[i] = (t == tstar[i]). Stores are
    // full-line, write-once, coalesced 1 KiB/wave, contiguous 256 KiB/block.
    float* outp = out + (size_t)b * T_STEPS * N_COLS + n0;
    #pragma unroll 8
    for (int t = 0; t < T_STEPS; ++t) {
        vfloat4 ov;
        #pragma unroll
        for (int i = 0; i < 4; ++i)
            ov[i] = (t == tstar[i]) ? 1.0f : 0.0f;
        *reinterpret_cast<vfloat4*>(outp) = ov;
        outp += N_COLS;
    }
}

extern "C" void kernel_launch(void* const* d_in, const int* in_sizes, int n_in,
                              void* d_out, int out_size, void* d_ws, size_t ws_size,
                              hipStream_t stream) {
    const float* x    = (const float*)d_in[0];   // [B, N] fp32
    const float* sens = (const float*)d_in[1];   // [N]    fp32
    float*       out  = (float*)d_out;           // [B, T, N] fp32

    const int N = in_sizes[1];                   // 1024
    const int B = in_sizes[0] / N;               // 2048
    (void)N; (void)out_size; (void)d_ws; (void)ws_size; (void)n_in;

    ttfs_encode_kernel<<<dim3(B), dim3(256), 0, stream>>>(x, sens, out);
}